// Round 1
// baseline (57.892 us; speedup 1.0000x reference)
//
#include <hip/hip_runtime.h>

// MQuantileLoss: B=4096 rows, N=8192 cols, fp32.
// quantiles(cumsum(row)) at q={.25,.5,.75} for both inputs, mean |diff|.

constexpr int BLOCK = 256;
constexpr int CHUNK = 32;          // elements per thread; BLOCK*CHUNK == NCOL
constexpr int NCOL  = 8192;

__global__ __launch_bounds__(BLOCK) void row_quantiles(
    const float* __restrict__ pe, const float* __restrict__ pt,
    float* __restrict__ qe, float* __restrict__ qt)
{
    const float* src = (blockIdx.y == 0) ? pe : pt;
    float*       dst = (blockIdx.y == 0) ? qe : qt;
    const int row = blockIdx.x;
    const int tid = threadIdx.x;
    const float* rp = src + (size_t)row * NCOL + (size_t)tid * CHUNK;

    // Load 32 contiguous floats into registers (8 x float4).
    float v[CHUNK];
    #pragma unroll
    for (int k = 0; k < CHUNK / 4; ++k) {
        const float4 f = *reinterpret_cast<const float4*>(rp + 4 * k);
        v[4*k+0] = f.x; v[4*k+1] = f.y; v[4*k+2] = f.z; v[4*k+3] = f.w;
    }
    float lsum = 0.f;
    #pragma unroll
    for (int k = 0; k < CHUNK; ++k) lsum += v[k];

    // Block exclusive scan of chunk sums.
    const int lane = tid & 63, wave = tid >> 6;
    float x = lsum;                       // wave inclusive scan
    #pragma unroll
    for (int off = 1; off < 64; off <<= 1) {
        const float y = __shfl_up(x, off, 64);
        if (lane >= off) x += y;
    }
    __shared__ float wsum[4];
    __shared__ float sbase[BLOCK + 1];    // monotone CDF bases, sbase[BLOCK]=total
    __shared__ float qscore[3];
    if (lane == 63) wsum[wave] = x;
    __syncthreads();
    float wbase = 0.f;
    #pragma unroll
    for (int w = 0; w < 4; ++w) if (w < wave) wbase += wsum[w];
    float excl = __shfl_up(x, 1, 64);
    if (lane == 0) excl = 0.f;
    sbase[tid] = wbase + excl;
    if (tid == BLOCK - 1) sbase[BLOCK] = wbase + x;
    __syncthreads();

    const float base  = sbase[tid];
    const float nbase = sbase[tid + 1];
    const float qs[3] = {0.25f, 0.5f, 0.75f};
    #pragma unroll
    for (int qi = 0; qi < 3; ++qi) {
        const float q = qs[qi];
        // Exactly one owner: sbase is monotone non-decreasing, sbase[0]==0 < q.
        const bool owner = (base < q && nbase >= q) ||
                           (tid == BLOCK - 1 && nbase < q);   // q > total: clip to N-1
        if (owner) {
            float run = base, prev = base;
            float Yb = 0.f, Ya = 0.f;
            int idx = -1;
            #pragma unroll
            for (int k = 0; k < CHUNK; ++k) {
                prev = run;
                run += v[k];
                if (idx < 0 && run >= q) { idx = k; Yb = run; Ya = prev; }
            }
            if (idx < 0) { idx = CHUNK - 1; Yb = run; Ya = prev; }  // rounding-gap / clip fallback
            // score = (i+1) + (q - cdf[i]) / (cdf[i] - cdf[i-1]);  Ya==0 when i==0.
            const float score = (float)(tid * CHUNK + idx + 1) + (q - Yb) / (Yb - Ya);
            qscore[qi] = score;
        }
    }
    __syncthreads();
    if (tid < 3) dst[row * 3 + tid] = qscore[tid];
}

__global__ __launch_bounds__(256) void reduce_absdiff(
    const float* __restrict__ qe, const float* __restrict__ qt,
    float* __restrict__ out, int n)
{
    const int tid = threadIdx.x;
    float s = 0.f;
    for (int i = tid; i < n; i += 256) s += fabsf(qe[i] - qt[i]);
    #pragma unroll
    for (int off = 32; off > 0; off >>= 1) s += __shfl_down(s, off, 64);
    __shared__ float ws[4];
    if ((tid & 63) == 0) ws[tid >> 6] = s;
    __syncthreads();
    if (tid == 0) out[0] = (ws[0] + ws[1] + ws[2] + ws[3]) / (float)n;
}

extern "C" void kernel_launch(void* const* d_in, const int* in_sizes, int n_in,
                              void* d_out, int out_size, void* d_ws, size_t ws_size,
                              hipStream_t stream) {
    const float* pe = (const float*)d_in[0];   // p_estimate
    const float* pt = (const float*)d_in[1];   // p_target
    const int B = in_sizes[0] / NCOL;
    float* qe = (float*)d_ws;                  // [B*3]
    float* qt = qe + (size_t)B * 3;            // [B*3]
    dim3 grid(B, 2);
    row_quantiles<<<grid, BLOCK, 0, stream>>>(pe, pt, qe, qt);
    reduce_absdiff<<<1, 256, 0, stream>>>(qe, qt, (float*)d_out, B * 3);
}